// Round 5
// baseline (582.781 us; speedup 1.0000x reference)
//
#include <hip/hip_runtime.h>
#include <stdint.h>

#define M_DIM 8192
#define N_DIM 4096
#define K_DIM 4096

typedef int v4i __attribute__((ext_vector_type(4)));

// ---------------------------------------------------------------------------
// async global->LDS copy, 16 B per lane (wave-uniform LDS base + lane*16)
// ---------------------------------------------------------------------------
typedef __attribute__((address_space(1))) const void gas_void;
typedef __attribute__((address_space(3))) void las_void;

__device__ __forceinline__ void async_copy16(const uint8_t* g, uint8_t* l) {
    __builtin_amdgcn_global_load_lds((gas_void*)g, (las_void*)l, 16, 0, 0);
}

__device__ __forceinline__ int quant1(float x, float scale) {
    // Matches jnp.clip(jnp.round(x/scale), -127, 127): IEEE fp32 divide +
    // round-to-nearest-even (v_rndne), then clamp.
    float q = __builtin_rintf(x / scale);
    q = fminf(127.0f, fmaxf(-127.0f, q));
    return (int)q;
}

__device__ __forceinline__ uint32_t pack4(int q0, int q1, int q2, int q3) {
    return (uint32_t)(q0 & 255) | ((uint32_t)(q1 & 255) << 8) |
           ((uint32_t)(q2 & 255) << 16) | ((uint32_t)(q3 & 255) << 24);
}

// ---------------------------------------------------------------------------
// Kernel 1: per-row absmax + quantize lhs -> qlhs [M][K] int8 row-major
// ---------------------------------------------------------------------------
__global__ __launch_bounds__(256) void quant_lhs_kernel(
    const float* __restrict__ lhs, uint8_t* __restrict__ qlhs,
    float* __restrict__ lhs_scale) {
    const int row = blockIdx.x;
    const int tid = threadIdx.x;
    const float4* src = (const float4*)(lhs + (size_t)row * K_DIM);

    float4 v[4];
    float m = 0.0f;
#pragma unroll
    for (int i = 0; i < 4; ++i) {
        v[i] = src[tid + i * 256];
        m = fmaxf(m, fmaxf(fmaxf(fabsf(v[i].x), fabsf(v[i].y)),
                           fmaxf(fabsf(v[i].z), fabsf(v[i].w))));
    }
#pragma unroll
    for (int off = 32; off > 0; off >>= 1)
        m = fmaxf(m, __shfl_down(m, off, 64));

    __shared__ float wmax[4];
    if ((tid & 63) == 0) wmax[tid >> 6] = m;
    __syncthreads();
    const float mm = fmaxf(fmaxf(wmax[0], wmax[1]), fmaxf(wmax[2], wmax[3]));
    const float scale = (mm == 0.0f) ? 1.0f : mm / 127.0f;
    if (tid == 0) lhs_scale[row] = scale;

    uint32_t* dst = (uint32_t*)(qlhs + (size_t)row * K_DIM);
#pragma unroll
    for (int i = 0; i < 4; ++i) {
        dst[tid + i * 256] = pack4(quant1(v[i].x, scale), quant1(v[i].y, scale),
                                   quant1(v[i].z, scale), quant1(v[i].w, scale));
    }
}

// ---------------------------------------------------------------------------
// Kernel 2a: rhs column absmax, float4-vectorized (4 cols/thread, 32 rows).
// atomicMax on float bits (monotone for non-negative floats).
// Grid: (N/1024, 128).
// ---------------------------------------------------------------------------
__global__ __launch_bounds__(256) void rhs_max_kernel(
    const float* __restrict__ rhs, uint32_t* __restrict__ maxbits) {
    const int c4 = (blockIdx.x * 256 + threadIdx.x) * 4;
    const int r0 = blockIdx.y * 32;
    float m0 = 0.0f, m1 = 0.0f, m2 = 0.0f, m3 = 0.0f;
#pragma unroll
    for (int r = 0; r < 32; ++r) {
        const float4 v = *(const float4*)(rhs + (size_t)(r0 + r) * N_DIM + c4);
        m0 = fmaxf(m0, fabsf(v.x));
        m1 = fmaxf(m1, fabsf(v.y));
        m2 = fmaxf(m2, fabsf(v.z));
        m3 = fmaxf(m3, fabsf(v.w));
    }
    atomicMax(&maxbits[c4 + 0], __float_as_uint(m0));
    atomicMax(&maxbits[c4 + 1], __float_as_uint(m1));
    atomicMax(&maxbits[c4 + 2], __float_as_uint(m2));
    atomicMax(&maxbits[c4 + 3], __float_as_uint(m3));
}

// ---------------------------------------------------------------------------
// Kernel 2b: quantize + transpose rhs -> qrhsT [N][K] int8 row-major.
// Scale computed inline from maxbits (same m/127.0f op as reference).
// Grid: (N/64, K/128) = (64, 32).
// ---------------------------------------------------------------------------
__global__ __launch_bounds__(256) void quant_rhs_t_kernel(
    const float* __restrict__ rhs, const uint32_t* __restrict__ maxbits,
    uint8_t* __restrict__ qrhsT) {
    __shared__ __align__(16) uint8_t tile[64 * 132];  // [n][k + 4B pad]
    const int nbase = blockIdx.x * 64;
    const int kbase = blockIdx.y * 128;
    const int tid = threadIdx.x;

    const int n0 = (tid & 15) * 4;
    float s[4];
#pragma unroll
    for (int j = 0; j < 4; ++j) {
        const float m = __uint_as_float(maxbits[nbase + n0 + j]);
        s[j] = (m == 0.0f) ? 1.0f : m / 127.0f;
    }

#pragma unroll
    for (int p = 0; p < 2; ++p) {
        const int k0 = (tid >> 4) * 4 + p * 64;
        int q[4][4];  // [i = k offset][j = n offset]
#pragma unroll
        for (int i = 0; i < 4; ++i) {
            const float4 v = *(const float4*)(
                rhs + (size_t)(kbase + k0 + i) * N_DIM + nbase + n0);
            q[i][0] = quant1(v.x, s[0]);
            q[i][1] = quant1(v.y, s[1]);
            q[i][2] = quant1(v.z, s[2]);
            q[i][3] = quant1(v.w, s[3]);
        }
#pragma unroll
        for (int j = 0; j < 4; ++j) {
            *(uint32_t*)(tile + (n0 + j) * 132 + k0) =
                pack4(q[0][j], q[1][j], q[2][j], q[3][j]);
        }
    }
    __syncthreads();

#pragma unroll
    for (int p = 0; p < 2; ++p) {
        const int c = tid + p * 256;
        const int n = c >> 3;
        const int g = c & 7;
        uint32_t d[4];
#pragma unroll
        for (int w = 0; w < 4; ++w)
            d[w] = *(const uint32_t*)(tile + n * 132 + g * 16 + w * 4);
        uint4 u;
        u.x = d[0]; u.y = d[1]; u.z = d[2]; u.w = d[3];
        *(uint4*)(qrhsT + (size_t)(nbase + n) * K_DIM + kbase + g * 16) = u;
    }
}

// ---------------------------------------------------------------------------
// Kernel 3: int8 GEMM, 256x256 tile, 8 waves (2Mx4N, 128x64 per wave).
//
// R5 design: A STREAMS GLOBAL->VGPR (no LDS), B through a 4-slot LDS ring.
// Rationale (R2-R4 counters): with both operands in LDS, the LDS unit is the
// saturated resource (~1500 cyc/tile > MFMA's 1306) and MFMA+LDS ran as a
// serial sum (~2530 cyc/tile) regardless of schedule. Moving A to direct
// global loads cuts per-tile LDS traffic 128 KB -> 48 KB (B reads 32 KB +
// B DMA 16 KB ~= 565 cyc, well under MFMA), and A's x4 intra-block read
// amplification is served by L1 (A slice/tile = 16 KB, fits 32 KB L1; the 4
// sharing waves are barrier-locked in time).
//
// Pipeline per tile t (A regs double-buffered X/Y):
//   issue 8 global_load_dwordx4: A(t+1) -> other buffer     [vm]
//   issue 2 global_load_lds:     B(t+3) -> slot (t+3)%4     [vm]
//   ds_read vb0..vb3 from slot t%4                          [lgkm]
//   setprio(1); lgkm(3/2/1/0) ladder, 8 MFMA per vb; setprio(0)
//   vmcnt(2)  -- A(t+1) and B(t+1) landed in every wave; B(t+3)'s 2 loads
//               stay in flight across the barrier (never drained to 0)
//   sched_barrier(0)  -- consumers of A(t+1) are register MFMAs (rule #18)
//   s_barrier
//
// B LDS slot (16 KB = 256 rows x 64 B): 16B chunk g of row r stored at chunk
// g ^ ((r>>1)&3) (zero-conflict swizzle, measured); applied on the global
// source address for staging (global_load_lds writes linearly) and on the
// ds_read address. A needs no swizzle (registers).
// ---------------------------------------------------------------------------
__global__ __launch_bounds__(512, 2) void gemm_i8_kernel(
    const uint8_t* __restrict__ qlhs, const uint8_t* __restrict__ qrhsT,
    const float* __restrict__ lhs_scale, const uint32_t* __restrict__ maxbits,
    float* __restrict__ out) {
    extern __shared__ __align__(16) uint8_t smem[];  // 4 * 16384 (B slots)

    const int tid = threadIdx.x;
    const int wave = tid >> 6;
    const int lane = tid & 63;

    // ---- XCD-aware tile swizzle: obid -> (xcd, local) -> 8x8 square
    const int obid = blockIdx.y * 16 + blockIdx.x;  // grid (16, 32)
    const int xcd = obid & 7;
    const int local = obid >> 3;                    // 0..63
    const int ty = (xcd >> 1) * 8 + (local >> 3);   // 0..31
    const int tx = (xcd & 1) * 8 + (local & 7);     // 0..15
    const int bm = ty * 256;
    const int bn = tx * 256;

    // ---- B staging map: thread t covers 16B chunk (row = t>>2, chunk = t&3)
    // of a 128-row x 64B half; source chunk pre-swizzled so LDS is linear.
    const int srow = tid >> 2;
    const int gsrc = (((tid & 3) ^ ((tid >> 3) & 3)) << 4);
    const uint8_t* gB = qrhsT + (size_t)(bn + srow) * K_DIM + gsrc;  // rows 0-127
    const uint8_t* gB2 = gB + (size_t)128 * K_DIM;                   // rows 128-255
    const uint32_t stO = (uint32_t)tid * 16u;

    // ---- wave tile: wm in {0,128}, wn in {0,64,128,192}
    const int wm = (wave >> 2) * 128;
    const int wn = (wave & 3) * 64;

    // ---- B fragment read map (within 16 KB slot): row = wn + f*16 +
    // (lane&15), chunk = (lane>>4) ^ ((lane>>1)&3)  (swizzled).
    const uint32_t fg = (uint32_t)((((lane >> 4) ^ ((lane >> 1) & 3)) << 4));
    const uint32_t boff = (uint32_t)((wn + (lane & 15)) * 64) + fg;

    // ---- A direct-load map: lane reads qlhs row (bm+wm+f*16+(lane&15)),
    // bytes (lane>>4)*16 + t*64; frag f at +f*16*K_DIM. No swizzle.
    const uint8_t* gAf =
        qlhs + (size_t)(bm + wm + (lane & 15)) * K_DIM + ((lane >> 4) * 16);
#define AFS ((size_t)16 * K_DIM)

    v4i acc[8][4] = {};

    // A register double-buffers
    v4i Xa0, Xa1, Xa2, Xa3, Xa4, Xa5, Xa6, Xa7;
    v4i Ya0, Ya1, Ya2, Ya3, Ya4, Ya5, Ya6, Ya7;

#define FENCE() asm volatile("" ::: "memory")
#define LGKM(n)                                                 \
    do {                                                        \
        asm volatile("s_waitcnt lgkmcnt(" #n ")" ::: "memory"); \
        __builtin_amdgcn_sched_barrier(0);                      \
    } while (0)
#define VMW(n)                                                 \
    do {                                                       \
        asm volatile("s_waitcnt vmcnt(" #n ")" ::: "memory");  \
        __builtin_amdgcn_sched_barrier(0);                     \
    } while (0)
#define MFMA8(C, ni, bv)                                                       \
    do {                                                                       \
        acc[0][ni] = __builtin_amdgcn_mfma_i32_16x16x64_i8(C##a0, bv,          \
                                                           acc[0][ni], 0, 0, 0); \
        acc[1][ni] = __builtin_amdgcn_mfma_i32_16x16x64_i8(C##a1, bv,          \
                                                           acc[1][ni], 0, 0, 0); \
        acc[2][ni] = __builtin_amdgcn_mfma_i32_16x16x64_i8(C##a2, bv,          \
                                                           acc[2][ni], 0, 0, 0); \
        acc[3][ni] = __builtin_amdgcn_mfma_i32_16x16x64_i8(C##a3, bv,          \
                                                           acc[3][ni], 0, 0, 0); \
        acc[4][ni] = __builtin_amdgcn_mfma_i32_16x16x64_i8(C##a4, bv,          \
                                                           acc[4][ni], 0, 0, 0); \
        acc[5][ni] = __builtin_amdgcn_mfma_i32_16x16x64_i8(C##a5, bv,          \
                                                           acc[5][ni], 0, 0, 0); \
        acc[6][ni] = __builtin_amdgcn_mfma_i32_16x16x64_i8(C##a6, bv,          \
                                                           acc[6][ni], 0, 0, 0); \
        acc[7][ni] = __builtin_amdgcn_mfma_i32_16x16x64_i8(C##a7, bv,          \
                                                           acc[7][ni], 0, 0, 0); \
    } while (0)

// CUR holds A(t) (loaded last tile); NXT receives A(t+1).
#define TILE(u, CUR, NXT, t)                                            \
    do {                                                                \
        const uint8_t* const Cs = smem + ((u) << 14);                   \
        uint8_t* const Ss = smem + ((((u) + 3) & 3) << 14);             \
        /* A(t+1) loads first (oldest vm ops -> drained by vmcnt(2)) */ \
        NXT##a0 = *(const v4i*)(gAf + 0 * AFS);                         \
        NXT##a1 = *(const v4i*)(gAf + 1 * AFS);                         \
        NXT##a2 = *(const v4i*)(gAf + 2 * AFS);                         \
        NXT##a3 = *(const v4i*)(gAf + 3 * AFS);                         \
        NXT##a4 = *(const v4i*)(gAf + 4 * AFS);                         \
        NXT##a5 = *(const v4i*)(gAf + 5 * AFS);                         \
        NXT##a6 = *(const v4i*)(gAf + 6 * AFS);                         \
        NXT##a7 = *(const v4i*)(gAf + 7 * AFS);                         \
        FENCE();                                                        \
        /* B(t+3) DMA (newest vm ops -> stay in flight) */              \
        async_copy16(gB, Ss + stO);                                     \
        async_copy16(gB2, Ss + 8192 + stO);                             \
        if ((t) < 60) { gB += 64; gB2 += 64; }                          \
        if ((t) < 62) { gAf += 64; }                                    \
        FENCE();                                                        \
        v4i vb0 = *(const v4i*)(Cs + boff + 0);                         \
        v4i vb1 = *(const v4i*)(Cs + boff + 1024);                      \
        v4i vb2 = *(const v4i*)(Cs + boff + 2048);                      \
        v4i vb3 = *(const v4i*)(Cs + boff + 3072);                      \
        FENCE();                                                        \
        __builtin_amdgcn_s_setprio(1);                                  \
        LGKM(3); MFMA8(CUR, 0, vb0);                                    \
        LGKM(2); MFMA8(CUR, 1, vb1);                                    \
        LGKM(1); MFMA8(CUR, 2, vb2);                                    \
        LGKM(0); MFMA8(CUR, 3, vb3);                                    \
        __builtin_amdgcn_s_setprio(0);                                  \
        VMW(2); /* A(t+1)+B(t+1) landed; B(t+3) in flight */            \
        __builtin_amdgcn_s_barrier();                                   \
    } while (0)

    // ---- prologue: A(0) into X (8 loads), then B(0),B(1),B(2) staged
    Xa0 = *(const v4i*)(gAf + 0 * AFS);
    Xa1 = *(const v4i*)(gAf + 1 * AFS);
    Xa2 = *(const v4i*)(gAf + 2 * AFS);
    Xa3 = *(const v4i*)(gAf + 3 * AFS);
    Xa4 = *(const v4i*)(gAf + 4 * AFS);
    Xa5 = *(const v4i*)(gAf + 5 * AFS);
    Xa6 = *(const v4i*)(gAf + 6 * AFS);
    Xa7 = *(const v4i*)(gAf + 7 * AFS);
    gAf += 64;  // -> tile 1
    FENCE();
#pragma unroll
    for (int p = 0; p < 3; ++p) {
        uint8_t* sb = smem + (p << 14);
        async_copy16(gB, sb + stO);
        async_copy16(gB2, sb + 8192 + stO);
        gB += 64;
        gB2 += 64;
    }
    VMW(4);  // A(0)+B(0) landed; B(1),B(2) in flight
    __builtin_amdgcn_s_barrier();

    // ---- main loop: 64 K-tiles of 64 bytes (X/Y alternate per tile)
#pragma unroll 1
    for (int tt = 0; tt < 64; tt += 4) {
        TILE(0, X, Y, tt + 0);
        TILE(1, Y, X, tt + 1);
        TILE(2, X, Y, tt + 2);
        TILE(3, Y, X, tt + 3);
    }
    // drain remaining DMA before epilogue
    asm volatile("s_waitcnt vmcnt(0)" ::: "memory");

    // ---- epilogue: C/D layout col=lane&15, row=(lane>>4)*4+reg
    const int r0 = bm + wm + (lane >> 4) * 4;
    const int c0 = bn + wn + (lane & 15);
    float rsv[4];
#pragma unroll
    for (int ni = 0; ni < 4; ++ni) {
        const float m = __uint_as_float(maxbits[c0 + ni * 16]);
        rsv[ni] = (m == 0.0f) ? 1.0f : m / 127.0f;
    }
#pragma unroll
    for (int mi = 0; mi < 8; ++mi) {
        float ls[4];
#pragma unroll
        for (int r = 0; r < 4; ++r) ls[r] = lhs_scale[r0 + mi * 16 + r];
#pragma unroll
        for (int ni = 0; ni < 4; ++ni) {
            float* o = out + (size_t)(r0 + mi * 16) * N_DIM + c0 + ni * 16;
#pragma unroll
            for (int r = 0; r < 4; ++r)
                o[(size_t)r * N_DIM] = (float)acc[mi][ni][r] * ls[r] * rsv[ni];
        }
    }
#undef FENCE
#undef LGKM
#undef VMW
#undef MFMA8
#undef TILE
#undef AFS
}

// ---------------------------------------------------------------------------
// Workspace layout (bytes):
//   qlhs   [0, 33554432)
//   qrhsT  [33554432, 50331648)
//   lhs_scale (float[8192])   @ 50331648
//   maxbits   (uint32[4096])  @ 50380800
// ---------------------------------------------------------------------------
extern "C" void kernel_launch(void* const* d_in, const int* in_sizes, int n_in,
                              void* d_out, int out_size, void* d_ws,
                              size_t ws_size, hipStream_t stream) {
    const float* lhs = (const float*)d_in[0];
    const float* rhs = (const float*)d_in[1];
    float* out = (float*)d_out;

    uint8_t* ws = (uint8_t*)d_ws;
    uint8_t* qlhs = ws;
    uint8_t* qrhsT = ws + 33554432u;
    float* lhs_scale = (float*)(ws + 50331648u);
    uint32_t* maxbits = (uint32_t*)(ws + 50380800u);

    static bool attr_set = false;
    if (!attr_set) {
        hipFuncSetAttribute((const void*)gemm_i8_kernel,
                            hipFuncAttributeMaxDynamicSharedMemorySize,
                            65536);
        attr_set = true;
    }

    hipMemsetAsync(maxbits, 0, N_DIM * sizeof(uint32_t), stream);

    quant_lhs_kernel<<<M_DIM, 256, 0, stream>>>(lhs, qlhs, lhs_scale);
    rhs_max_kernel<<<dim3(N_DIM / 1024, 128), 256, 0, stream>>>(rhs, maxbits);
    quant_rhs_t_kernel<<<dim3(N_DIM / 64, K_DIM / 128), 256, 0, stream>>>(
        rhs, maxbits, qrhsT);
    gemm_i8_kernel<<<dim3(16, 32), 512, 65536, stream>>>(
        qlhs, qrhsT, lhs_scale, maxbits, out);
}